// Round 3
// baseline (252.495 us; speedup 1.0000x reference)
//
#include <hip/hip_runtime.h>
#include <hip/hip_fp16.h>

#define HH 28
#define WW 28
#define NPIX 784
#define NIMG 32            // images per group (8 float4 chunks)
#define BLOCK 768          // 12 waves, 3/SIMD
#define NTASK (NPIX * 8)   // 6272 (pixel, chunk) tasks; also (q, chunk) stage tasks
#define MAXT 9             // ceil(6272/768)

// LDS layout: buf[q*8 + (c ^ (q&7))] holds images 4c..4c+3 of pixel q.
// - stage write: aligned 8 lanes = fixed q, c=0..7 -> XOR slot permutation -> 128 B, 32 banks, conflict-free
// - gather read: aligned 8 lanes = fixed p (same q per tap), c=0..7 -> same property, conflict-free
//   INDEPENDENT of center jitter. This removes the structural 1.6x bank-conflict tax of lane=pixel layouts.
__global__ __launch_bounds__(BLOCK, 3) void axs_89807766159734_kernel(
    const float* __restrict__ x, const float* __restrict__ pos2d,
    const float* __restrict__ weight, float* __restrict__ out, int nGroups)
{
    __shared__ float4 buf[NTASK];              // 100,352 B
    __shared__ __half ctab[NPIX][26];          // 40,768 B: 25 f16 coefs + zero pad
    __shared__ short  sce0[NPIX], sce1[NPIX];  // 3,136 B: rounded centers
    // total 144,256 B < 160 KiB -> 1 block/CU

    const int tid = threadIdx.x;

    // ---- one-time: coef table (exp amortized over all 4 groups this block does) ----
    for (int p = tid; p < NPIX; p += BLOCK) {
        const float p0 = pos2d[2*p], p1 = pos2d[2*p+1];
        const float sw = fmaxf(weight[p], 0.f);            // relu(weight)
        const float ce0 = rintf(p0), ce1 = rintf(p1);      // == jnp.round (half-even)
        sce0[p] = (short)(int)ce0;
        sce1[p] = (short)(int)ce1;
#pragma unroll
        for (int t = 0; t < 25; ++t) {
            const int i0 = t/5 - 2, i1 = t%5 - 2;
            const float cr0 = ce0 + (float)i0, cr1 = ce1 + (float)i1;
            const int c0 = (int)cr0, c1 = (int)cr1;
            const bool inb = (c0>=0)&(c0<HH)&(c1>=0)&(c1<WW);
            const float d0 = cr0-p0, d1 = cr1-p1;
            const float w = __expf(-0.5f*(d0*d0+d1*d1));
            ctab[p][t] = __float2half(inb ? sw*w : 0.f);   // mask+sw folded; f16 err ~1e-4, budget 3.7e-2
        }
        ctab[p][25] = __float2half(0.f);
    }

    // ---- prefetch first group's staging into registers ----
    int g = blockIdx.x;
    float4 pre[MAXT];
    if (g < nGroups) {
        int k = 0;
        for (int s = tid; s < NTASK; s += BLOCK, ++k) {
            const int q = s >> 3, c = s & 7;
            const int ib = (g*NIMG + 4*c)*NPIX + q;        // 8x32B segments/wave-load
            pre[k] = make_float4(x[ib], x[ib+NPIX], x[ib+2*NPIX], x[ib+3*NPIX]);
        }
    }

    for (; g < nGroups; g += gridDim.x) {
        __syncthreads();                                   // prev compute done (also guards table init)
        {
            int k = 0;
            for (int s = tid; s < NTASK; s += BLOCK, ++k) {
                const int q = s >> 3, c = s & 7;
                buf[q*8 + (c ^ (q & 7))] = pre[k];         // conflict-free ds_write_b128
            }
        }
        __syncthreads();

        // prefetch next group during compute (HBM ~10k cyc hidden under ~24k cyc DS)
        const int gn = g + gridDim.x;
        if (gn < nGroups) {
            int k = 0;
            for (int s = tid; s < NTASK; s += BLOCK, ++k) {
                const int q = s >> 3, c = s & 7;
                const int ib = (gn*NIMG + 4*c)*NPIX + q;
                pre[k] = make_float4(x[ib], x[ib+NPIX], x[ib+2*NPIX], x[ib+3*NPIX]);
            }
        }

        for (int tau = tid; tau < NTASK; tau += BLOCK) {
            const int p = tau >> 3, c = tau & 7;
            const int e0 = sce0[p], e1 = sce1[p];          // broadcast reads (8 lanes share p)
            uint cw[13];
            {
                const uint* crow = (const uint*)&ctab[p][0];
#pragma unroll
                for (int j = 0; j < 13; ++j) cw[j] = crow[j];   // 13x ds_read_b32, broadcast
            }
            float4 acc = make_float4(0.f,0.f,0.f,0.f);
#pragma unroll
            for (int t = 0; t < 25; ++t) {
                const int i0 = t/5 - 2, i1 = t%5 - 2;
                int c0 = e0 + i0; c0 = min(max(c0,0), HH-1);
                int c1 = e1 + i1; c1 = min(max(c1,0), WW-1);
                const int q = c0*WW + c1;
                const float4 v = buf[q*8 + (c ^ (q & 7))]; // conflict-free ds_read_b128
                const __half2 h2 = *(const __half2*)&cw[t>>1];
                const float coef = __half2float((t&1) ? __high2half(h2) : __low2half(h2));
                acc.x = fmaf(coef, v.x, acc.x);
                acc.y = fmaf(coef, v.y, acc.y);
                acc.z = fmaf(coef, v.z, acc.z);
                acc.w = fmaf(coef, v.w, acc.w);
            }
            const int ob = (g*NIMG + 4*c)*NPIX + p;        // 8x32B segments/wave-store, L2 merges
            out[ob]        = acc.x;
            out[ob+NPIX]   = acc.y;
            out[ob+2*NPIX] = acc.z;
            out[ob+3*NPIX] = acc.w;
        }
    }
}

extern "C" void kernel_launch(void* const* d_in, const int* in_sizes, int n_in,
                              void* d_out, int out_size, void* d_ws, size_t ws_size,
                              hipStream_t stream) {
    const float* x      = (const float*)d_in[0];   // (32768,1,28,28) fp32
    const float* pos2d  = (const float*)d_in[1];   // (28,28,2) fp32
    const float* weight = (const float*)d_in[2];   // (28,28) fp32
    float* out = (float*)d_out;

    const int B = in_sizes[0] / NPIX;              // 32768
    const int nGroups = B / NIMG;                  // 1024
    const int blocks = 256;                        // 1 block/CU, 4 groups each

    hipLaunchKernelGGL(axs_89807766159734_kernel, dim3(blocks), dim3(BLOCK), 0, stream,
                       x, pos2d, weight, out, nGroups);
}